// Round 18
// baseline (100.903 us; speedup 1.0000x reference)
//
#include <hip/hip_runtime.h>
#include <hip/hip_bf16.h>

#define BATCH 64
#define IN_CH 128
#define ILEN  512
#define OLEN  505
#define OCH   128
#define KDIM  1024    // IN_CH * 8
#define BK    64      // K per chunk
#define NCHK  16      // KDIM / BK
#define NWG   OLEN

typedef float  f32x4   __attribute__((ext_vector_type(4)));
typedef float  f32x16  __attribute__((ext_vector_type(16)));
typedef short  bf16x8  __attribute__((ext_vector_type(8)));
typedef unsigned short u16x8 __attribute__((ext_vector_type(8)));

__device__ __forceinline__ unsigned short f2bfu(float f) {
  union { __hip_bfloat16 h; unsigned short s; } u;
  u.h = __float2bfloat16(f);
  return u.s;
}
__device__ __forceinline__ short f2bf(float f) { return (short)f2bfu(f); }
__device__ __forceinline__ float bf2f(unsigned short s) {
  union { unsigned int u; float f; } u;
  u.u = ((unsigned int)s) << 16;
  return u.f;
}

// ============ MAIN: R14 skeleton (verified) + 32x32x16 MFMA consume ============
// Staging maps, swizzles, vmcnt schedule, barriers: R14-verbatim.
// Consume: wave wn owns o-column [wn*32, wn*32+32) (oh = wn>>1), 2 row-tiles
// bt (b 0..31 / 32..63). Per iter: 8 afr b128 + 8 B f32x4 reads (256 B, was
// 384) + 8 mfma_32x32x16 (was 16 mfma_16x16x32). A-frag: row=lane&31,
// k=(lane>>5)*8+j (same contiguous-16B pattern as the verified 16x16x32).
template <bool USE_TMP>
__global__ __launch_bounds__(256, 2) void lc1d_main(
    const float* __restrict__ x, const float* __restrict__ w,
    const float* __restrict__ bias, void* __restrict__ outp) {
  const int orig = blockIdx.x;
  const int xcd = orig & 7, idx = orig >> 3;
  const int q = NWG / 8, rm = NWG % 8;
  const int l = (xcd < rm ? xcd * (q + 1) : rm * (q + 1) + (xcd - rm) * q) + idx;

  const int tid  = threadIdx.x;
  const int lane = tid & 63;
  const int wn   = tid >> 6;        // wave 0..3 -> o column [wn*32, wn*32+32)
  const int r2   = lane & 31;
  const int h2   = lane >> 5;       // 0..1 : k-group within k-step

  __shared__ float Bs[2][2][BK * 64];   // R14 layout: [buf][oh][ob*64 + c'*4]
  __shared__ short As[2][BK * 64];      // R14 layout: [buf][b*64 + (c^(b&7))*8...]

  f32x16 acc[2];                        // [bt] : 32x32 tile accumulators
  acc[0] = (f32x16)(0.f);
  acc[1] = (f32x16)(0.f);

  const float* __restrict__ wl = w + (size_t)l * (OCH * KDIM);

  // ---- B staging map (R14-verbatim) ----
  const int so  = tid >> 4;
  const int sc  = tid & 15;
  const int ssw = ((so & 7) << 1) | ((so >> 3) & 1);
  // ---- A staging map (R14-verbatim) ----
  const int kk  = tid & 63;
  const int tb  = tid >> 6;
  const int il  = kk >> 3;
  const int kof = kk & 7;

  float aa0[16], aa1[16];

  auto loadA = [&](float (&aa)[16], int kc) {
    const float* xb = x + (size_t)(kc * 8 + il) * ILEN + l + kof;
#pragma unroll
    for (int it = 0; it < 16; ++it)
      aa[it] = xb[(size_t)(it * 4 + tb) * (IN_CH * ILEN)];
  };
  auto writeA = [&](const float (&aa)[16], int buf) {
#pragma unroll
    for (int it = 0; it < 16; ++it) {
      const int b = it * 4 + tb;
      As[buf][b * 64 + (kk ^ ((b & 7) << 3))] = f2bf(aa[it]);
    }
  };
  auto stageB = [&](int buf, int kc, int oh) {
    const float* wo = wl + (size_t)oh * 64 * KDIM;
#pragma unroll
    for (int it = 0; it < 4; ++it) {
      const int ob = it * 16 + so;
      const float* src = wo + (size_t)ob * KDIM + kc * BK + (sc ^ ssw) * 4;
      __builtin_amdgcn_global_load_lds(
          (const __attribute__((address_space(1))) void*)src,
          (__attribute__((address_space(3))) void*)&Bs[buf][oh][ob * 64 + sc * 4],
          16, 0, 0);
    }
  };

  // consume: my wave's o-row in Bs: oh = wn>>1, ol = (wn&1)*32 + r2
  const int ohw = wn >> 1;
  const int ol  = (wn & 1) * 32 + r2;
  const int rsw = ((r2 & 7) << 1) | ((r2 >> 3) & 1);   // == ssw(ol), verified
  auto computeBoth = [&](int cur) {
#pragma unroll
    for (int kb = 0; kb < 2; ++kb) {     // 2 batches x 2 k-steps
      bf16x8 af[2][2];                   // [bt][s2]
      f32x4  bw[2][2];                   // [s2][lo/hi]
#pragma unroll
      for (int s2 = 0; s2 < 2; ++s2) {
        const int s = kb * 2 + s2;       // k-step 0..3 (K=16 each)
        const int cA = s * 2 + h2;       // A chunk index 0..7
#pragma unroll
        for (int bt = 0; bt < 2; ++bt) {
          const int b = bt * 32 + r2;
          af[bt][s2] = *reinterpret_cast<const bf16x8*>(
              &As[cur][b * 64 + ((cA ^ (b & 7)) << 3)]);
        }
        const int c0 = s * 4 + h2 * 2;   // fp32 16B-chunk index 0..15
        bw[s2][0] = *reinterpret_cast<const f32x4*>(
            &Bs[cur][ohw][ol * 64 + ((c0) ^ rsw) * 4]);
        bw[s2][1] = *reinterpret_cast<const f32x4*>(
            &Bs[cur][ohw][ol * 64 + ((c0 + 1) ^ rsw) * 4]);
      }
      bf16x8 bf[2];
#pragma unroll
      for (int s2 = 0; s2 < 2; ++s2)
#pragma unroll
        for (int j = 0; j < 4; ++j) {
          bf[s2][j]     = f2bf(bw[s2][0][j]);
          bf[s2][4 + j] = f2bf(bw[s2][1][j]);
        }
      // pure-MFMA stretch (DS pipe free for B-DMA landing)
#pragma unroll
      for (int s2 = 0; s2 < 2; ++s2) {
        acc[0] = __builtin_amdgcn_mfma_f32_32x32x16_bf16(af[0][s2], bf[s2], acc[0], 0, 0, 0);
        acc[1] = __builtin_amdgcn_mfma_f32_32x32x16_bf16(af[1][s2], bf[s2], acc[1], 0, 0, 0);
      }
    }
  };

  // ---- prologue + schedule (R14-verbatim) ----
  loadA(aa0, 0);
  stageB(0, 0, 0);
  stageB(0, 0, 1);
  writeA(aa0, 0);
  loadA(aa1, 1);
  asm volatile("s_waitcnt vmcnt(16) lgkmcnt(0)" ::: "memory");
  __builtin_amdgcn_sched_barrier(0);
  __builtin_amdgcn_s_barrier();
  __builtin_amdgcn_sched_barrier(0);

  auto step = [&](int kc, float (&aaW)[16], float (&aaL)[16]) {
    if (kc + 1 < NCHK) {
      const int nxt = (kc + 1) & 1;
      stageB(nxt, kc + 1, 0);
      stageB(nxt, kc + 1, 1);
    }
    if (kc + 2 < NCHK) loadA(aaL, kc + 2);
    __builtin_amdgcn_sched_barrier(0);
    computeBoth(kc & 1);
    if (kc + 1 < NCHK) {
      writeA(aaW, (kc + 1) & 1);
      if (kc + 2 < NCHK) {
        asm volatile("s_waitcnt vmcnt(16) lgkmcnt(0)" ::: "memory");
      } else {
        asm volatile("s_waitcnt vmcnt(0) lgkmcnt(0)" ::: "memory");
      }
      __builtin_amdgcn_sched_barrier(0);
      __builtin_amdgcn_s_barrier();
      __builtin_amdgcn_sched_barrier(0);
    }
  };

  for (int kc = 0; kc < NCHK; kc += 2) {
    step(kc, aa1, aa0);
    step(kc + 1, aa0, aa1);
  }

  // ---- epilogue: 32x32 C/D (m74/m101): col=lane&31, row=(q&3)+8*(q>>2)+4*h2 ----
  const int og = wn * 32 + r2;    // global o (wn covers all 128 o)
  if (USE_TMP) {
    unsigned short* t = (unsigned short*)outp + (size_t)l * (BATCH * OCH) + og;
#pragma unroll
    for (int bt = 0; bt < 2; ++bt)
#pragma unroll
      for (int qq = 0; qq < 16; ++qq) {
        const int row = (qq & 3) + 8 * (qq >> 2) + 4 * h2;
        const int b   = bt * 32 + row;
        t[(size_t)b * OCH] = f2bfu(acc[bt][qq]);
      }
  } else {
    const float bv = bias[og * OLEN + l];
#pragma unroll
    for (int bt = 0; bt < 2; ++bt)
#pragma unroll
      for (int qq = 0; qq < 16; ++qq) {
        const int row = (qq & 3) + 8 * (qq >> 2) + 4 * h2;
        const int b   = bt * 32 + row;
        ((float*)outp)[(size_t)b * (OCH * OLEN) + (size_t)og * OLEN + l] =
            acc[bt][qq] + bv;
      }
  }
}

// tmp(bf16)[l][b][o] -> out(f32)[b][o][l] (+bias), 64x64 tile (R14-verified)
__global__ __launch_bounds__(256) void lc1d_tr(const unsigned short* __restrict__ tmp,
                                               const float* __restrict__ bias,
                                               float* __restrict__ out) {
  const int l0  = blockIdx.x * 64;
  const int bo0 = blockIdx.y * 64;
  const int tid = threadIdx.x;
  __shared__ float t[64][65];

  const int boj = tid & 63, lq = tid >> 6;
#pragma unroll
  for (int rr = 0; rr < 16; ++rr) {
    const int li = rr * 4 + lq;
    const int l  = l0 + li;
    if (l < OLEN)
      t[li][boj] = bf2f(tmp[(size_t)l * (BATCH * OCH) + bo0 + boj]);
  }
  __syncthreads();
  const int lj = tid & 63, bq = tid >> 6;
  const int l  = l0 + lj;
#pragma unroll
  for (int rr = 0; rr < 16; ++rr) {
    const int bl = rr * 4 + bq;
    const int bo = bo0 + bl;
    if (l < OLEN) {
      const int oc = bo & (OCH - 1);
      out[(size_t)bo * OLEN + l] = t[lj][bl] + bias[oc * OLEN + l];
    }
  }
}

extern "C" void kernel_launch(void* const* d_in, const int* in_sizes, int n_in,
                              void* d_out, int out_size, void* d_ws, size_t ws_size,
                              hipStream_t stream) {
  const float* x    = (const float*)d_in[0];
  const float* w    = (const float*)d_in[1];
  const float* bias = (const float*)d_in[2];
  float* out        = (float*)d_out;

  const size_t need = (size_t)OLEN * BATCH * OCH * sizeof(unsigned short);  // 8.3 MB
  if (ws_size >= need) {
    unsigned short* tmp = (unsigned short*)d_ws;
    lc1d_main<true><<<dim3(NWG), 256, 0, stream>>>(x, w, bias, (void*)tmp);
    lc1d_tr<<<dim3(8, 128), 256, 0, stream>>>(tmp, bias, out);
  } else {
    lc1d_main<false><<<dim3(NWG), 256, 0, stream>>>(x, w, bias, (void*)out);
  }
}

// Round 19
// 95.203 us; speedup vs baseline: 1.0599x; 1.0599x over previous
//
#include <hip/hip_runtime.h>
#include <hip/hip_bf16.h>

#define BATCH 64
#define IN_CH 128
#define ILEN  512
#define OLEN  505
#define OCH   128
#define KDIM  1024    // IN_CH * 8
#define BK    64      // K per chunk
#define NCHK  16      // KDIM / BK
#define NWG   OLEN

typedef float  f32x4  __attribute__((ext_vector_type(4)));
typedef short  bf16x8 __attribute__((ext_vector_type(8)));

__device__ __forceinline__ unsigned short f2bfu(float f) {
  union { __hip_bfloat16 h; unsigned short s; } u;
  u.h = __float2bfloat16(f);
  return u.s;
}
__device__ __forceinline__ short f2bf(float f) { return (short)f2bfu(f); }
__device__ __forceinline__ float bf2f(unsigned short s) {
  union { unsigned int u; float f; } u;
  u.u = ((unsigned int)s) << 16;
  return u.f;
}

// ============ FINAL: R14 configuration (best measured: 93.3 us) ============
// Per block (l): GEMM M=64(b) x N=128(o) x K=1024 via mfma_16x16x32_bf16.
// - B (weights, 258MB HBM stream): global_load_lds 16B direct-to-LDS fp32,
//   double-buffered, source-swizzled; counted vmcnt(16) -> next chunk's loads
//   stay in flight across the barrier (never drained mid-loop).
// - A (x window, L2-resident): reg-staged f32 -> bf16 XOR-swizzled LDS, dbuf.
// - Consume: per ks, ALL unique LDS reads batched into regs first (8 afr
//   shared across both oh halves + 4 B-words), then a pure-MFMA stretch
//   frees the DS pipe for the in-flight B-DMA writes to land (the -8% lever).
// - Output: bf16 tmp[l][b][o] (coalesced) + transpose kernel (+bias, fp32).
template <bool USE_TMP>
__global__ __launch_bounds__(256, 2) void lc1d_main(
    const float* __restrict__ x, const float* __restrict__ w,
    const float* __restrict__ bias, void* __restrict__ outp) {
  const int orig = blockIdx.x;
  const int xcd = orig & 7, idx = orig >> 3;
  const int q = NWG / 8, rm = NWG % 8;
  const int l = (xcd < rm ? xcd * (q + 1) : rm * (q + 1) + (xcd - rm) * q) + idx;

  const int tid  = threadIdx.x;
  const int lane = tid & 63;
  const int wn   = tid >> 6;
  const int r    = lane & 15;
  const int h    = lane >> 4;

  __shared__ float Bs[2][2][BK * 64];
  __shared__ short As[2][BK * 64];

  f32x4 acc[2][4];
#pragma unroll
  for (int oh = 0; oh < 2; ++oh)
#pragma unroll
    for (int m = 0; m < 4; ++m) acc[oh][m] = (f32x4){0.f, 0.f, 0.f, 0.f};

  const float* __restrict__ wl = w + (size_t)l * (OCH * KDIM);

  const int so  = tid >> 4;
  const int sc  = tid & 15;
  const int ssw = ((so & 7) << 1) | ((so >> 3) & 1);

  const int kk  = tid & 63;
  const int tb  = tid >> 6;
  const int il  = kk >> 3;
  const int kof = kk & 7;

  float aa0[16], aa1[16];

  auto loadA = [&](float (&aa)[16], int kc) {
    const float* xb = x + (size_t)(kc * 8 + il) * ILEN + l + kof;
#pragma unroll
    for (int it = 0; it < 16; ++it)
      aa[it] = xb[(size_t)(it * 4 + tb) * (IN_CH * ILEN)];
  };
  auto writeA = [&](const float (&aa)[16], int buf) {
#pragma unroll
    for (int it = 0; it < 16; ++it) {
      const int b = it * 4 + tb;
      As[buf][b * 64 + (kk ^ ((b & 7) << 3))] = f2bf(aa[it]);
    }
  };
  auto stageB = [&](int buf, int kc, int oh) {
    const float* wo = wl + (size_t)oh * 64 * KDIM;
#pragma unroll
    for (int it = 0; it < 4; ++it) {
      const int ob = it * 16 + so;
      const float* src = wo + (size_t)ob * KDIM + kc * BK + (sc ^ ssw) * 4;
      __builtin_amdgcn_global_load_lds(
          (const __attribute__((address_space(1))) void*)src,
          (__attribute__((address_space(3))) void*)&Bs[buf][oh][ob * 64 + sc * 4],
          16, 0, 0);
    }
  };

  const int rsw = ((r & 7) << 1) | ((r >> 3) & 1);
  auto computeBoth = [&](int cur) {
    const int ob = wn * 16 + r;
#pragma unroll
    for (int ks = 0; ks < 2; ++ks) {
      const int c0 = ks * 8 + h * 2;
      bf16x8 af[4];
#pragma unroll
      for (int mt = 0; mt < 4; ++mt) {
        const int b = mt * 16 + r;
        af[mt] = *reinterpret_cast<const bf16x8*>(
            &As[cur][b * 64 + ((ks * 32 + h * 8) ^ ((b & 7) << 3))]);
      }
      const f32x4 b0lo = *reinterpret_cast<const f32x4*>(
          &Bs[cur][0][ob * 64 + ((c0) ^ rsw) * 4]);
      const f32x4 b0hi = *reinterpret_cast<const f32x4*>(
          &Bs[cur][0][ob * 64 + ((c0 + 1) ^ rsw) * 4]);
      const f32x4 b1lo = *reinterpret_cast<const f32x4*>(
          &Bs[cur][1][ob * 64 + ((c0) ^ rsw) * 4]);
      const f32x4 b1hi = *reinterpret_cast<const f32x4*>(
          &Bs[cur][1][ob * 64 + ((c0 + 1) ^ rsw) * 4]);
      bf16x8 bf0, bf1;
#pragma unroll
      for (int j = 0; j < 4; ++j) {
        bf0[j] = f2bf(b0lo[j]); bf0[4 + j] = f2bf(b0hi[j]);
        bf1[j] = f2bf(b1lo[j]); bf1[4 + j] = f2bf(b1hi[j]);
      }
#pragma unroll
      for (int mt = 0; mt < 4; ++mt)
        acc[0][mt] = __builtin_amdgcn_mfma_f32_16x16x32_bf16(af[mt], bf0, acc[0][mt], 0, 0, 0);
#pragma unroll
      for (int mt = 0; mt < 4; ++mt)
        acc[1][mt] = __builtin_amdgcn_mfma_f32_16x16x32_bf16(af[mt], bf1, acc[1][mt], 0, 0, 0);
    }
  };

  loadA(aa0, 0);
  stageB(0, 0, 0);
  stageB(0, 0, 1);
  writeA(aa0, 0);
  loadA(aa1, 1);
  asm volatile("s_waitcnt vmcnt(16) lgkmcnt(0)" ::: "memory");
  __builtin_amdgcn_sched_barrier(0);
  __builtin_amdgcn_s_barrier();
  __builtin_amdgcn_sched_barrier(0);

  auto step = [&](int kc, float (&aaW)[16], float (&aaL)[16]) {
    if (kc + 1 < NCHK) {
      const int nxt = (kc + 1) & 1;
      stageB(nxt, kc + 1, 0);
      stageB(nxt, kc + 1, 1);
    }
    if (kc + 2 < NCHK) loadA(aaL, kc + 2);
    __builtin_amdgcn_sched_barrier(0);
    computeBoth(kc & 1);
    if (kc + 1 < NCHK) {
      writeA(aaW, (kc + 1) & 1);
      if (kc + 2 < NCHK) {
        asm volatile("s_waitcnt vmcnt(16) lgkmcnt(0)" ::: "memory");
      } else {
        asm volatile("s_waitcnt vmcnt(0) lgkmcnt(0)" ::: "memory");
      }
      __builtin_amdgcn_sched_barrier(0);
      __builtin_amdgcn_s_barrier();
      __builtin_amdgcn_sched_barrier(0);
    }
  };

  for (int kc = 0; kc < NCHK; kc += 2) {
    step(kc, aa1, aa0);
    step(kc + 1, aa0, aa1);
  }

#pragma unroll
  for (int oh = 0; oh < 2; ++oh) {
    const int og = oh * 64 + wn * 16 + r;
    if (USE_TMP) {
      unsigned short* t = (unsigned short*)outp + (size_t)l * (BATCH * OCH) + og;
#pragma unroll
      for (int mt = 0; mt < 4; ++mt)
#pragma unroll
        for (int j = 0; j < 4; ++j) {
          const int b = mt * 16 + h * 4 + j;
          t[(size_t)b * OCH] = f2bfu(acc[oh][mt][j]);
        }
    } else {
      const float bv = bias[og * OLEN + l];
#pragma unroll
      for (int mt = 0; mt < 4; ++mt)
#pragma unroll
        for (int j = 0; j < 4; ++j) {
          const int b = mt * 16 + h * 4 + j;
          ((float*)outp)[(size_t)b * (OCH * OLEN) + (size_t)og * OLEN + l] =
              acc[oh][mt][j] + bv;
        }
    }
  }
}

// tmp(bf16)[l][b][o] -> out(f32)[b][o][l] (+bias), 64x64 LDS tile transpose
__global__ __launch_bounds__(256) void lc1d_tr(const unsigned short* __restrict__ tmp,
                                               const float* __restrict__ bias,
                                               float* __restrict__ out) {
  const int l0  = blockIdx.x * 64;
  const int bo0 = blockIdx.y * 64;
  const int tid = threadIdx.x;
  __shared__ float t[64][65];

  const int boj = tid & 63, lq = tid >> 6;
#pragma unroll
  for (int rr = 0; rr < 16; ++rr) {
    const int li = rr * 4 + lq;
    const int l  = l0 + li;
    if (l < OLEN)
      t[li][boj] = bf2f(tmp[(size_t)l * (BATCH * OCH) + bo0 + boj]);
  }
  __syncthreads();
  const int lj = tid & 63, bq = tid >> 6;
  const int l  = l0 + lj;
#pragma unroll
  for (int rr = 0; rr < 16; ++rr) {
    const int bl = rr * 4 + bq;
    const int bo = bo0 + bl;
    if (l < OLEN) {
      const int oc = bo & (OCH - 1);
      out[(size_t)bo * OLEN + l] = t[lj][bl] + bias[oc * OLEN + l];
    }
  }
}

extern "C" void kernel_launch(void* const* d_in, const int* in_sizes, int n_in,
                              void* d_out, int out_size, void* d_ws, size_t ws_size,
                              hipStream_t stream) {
  const float* x    = (const float*)d_in[0];
  const float* w    = (const float*)d_in[1];
  const float* bias = (const float*)d_in[2];
  float* out        = (float*)d_out;

  const size_t need = (size_t)OLEN * BATCH * OCH * sizeof(unsigned short);  // 8.3 MB
  if (ws_size >= need) {
    unsigned short* tmp = (unsigned short*)d_ws;
    lc1d_main<true><<<dim3(NWG), 256, 0, stream>>>(x, w, bias, (void*)tmp);
    lc1d_tr<<<dim3(8, 128), 256, 0, stream>>>(tmp, bias, out);
  } else {
    lc1d_main<false><<<dim3(NWG), 256, 0, stream>>>(x, w, bias, (void*)out);
  }
}